// Round 1
// baseline (135.378 us; speedup 1.0000x reference)
//
#include <hip/hip_runtime.h>

#define NTOK 2048
#define NEGV -9.0e15f

// ---------------- Kernel A: Wh = h@W, f1 = Wh@a1, f2 = Wh@a2 ----------------
__global__ __launch_bounds__(256) void gat_pre(
    const float* __restrict__ h, const float* __restrict__ W,
    const float* __restrict__ a, float* __restrict__ Wh,
    float* __restrict__ f1, float* __restrict__ f2) {
  __shared__ float wL[128 * 64];   // 32 KB
  __shared__ float hL[16 * 128];   // 8 KB, 16 rows per block
  int t = threadIdx.x;
  {
    const float4* W4 = (const float4*)W;
    float4* wL4 = (float4*)wL;
#pragma unroll
    for (int k = 0; k < 8; ++k) wL4[t + 256 * k] = W4[t + 256 * k];
    const float4* h4 = (const float4*)(h + (size_t)blockIdx.x * 16 * 128);
    float4* hL4 = (float4*)hL;
#pragma unroll
    for (int k = 0; k < 2; ++k) hL4[t + 256 * k] = h4[t + 256 * k];
  }
  __syncthreads();
  int w = t >> 6, lane = t & 63;
  float acc[4] = {0.f, 0.f, 0.f, 0.f};
  for (int kc = 0; kc < 128; kc += 32) {
    float wreg[32];
#pragma unroll
    for (int kk = 0; kk < 32; ++kk) wreg[kk] = wL[(kc + kk) * 64 + lane];
#pragma unroll
    for (int r = 0; r < 4; ++r) {
      const float* hrow = &hL[(w * 4 + r) * 128 + kc];
#pragma unroll
      for (int kk = 0; kk < 32; kk += 4) {
        float4 hv = *(const float4*)(hrow + kk);
        acc[r] += hv.x * wreg[kk] + hv.y * wreg[kk + 1] +
                  hv.z * wreg[kk + 2] + hv.w * wreg[kk + 3];
      }
    }
  }
  float a1 = a[lane], a2 = a[lane + 64];
  int row0 = blockIdx.x * 16 + w * 4;
#pragma unroll
  for (int r = 0; r < 4; ++r) {
    int row = row0 + r;
    Wh[(size_t)row * 64 + lane] = acc[r];
    float v1 = acc[r] * a1, v2 = acc[r] * a2;
#pragma unroll
    for (int s = 32; s; s >>= 1) {
      v1 += __shfl_xor(v1, s, 64);
      v2 += __shfl_xor(v2, s, 64);
    }
    if (lane == 0) { f1[row] = v1; f2[row] = v2; }
  }
}

// ------- Kernel B: masked softmax of rank-1 scores + PV matvec + ELU --------
// grid (256, 8): blockIdx.x = 8-row tile, blockIdx.y = batch. 512 threads.
__global__ __launch_bounds__(512, 4) void gat_main(
    const int* __restrict__ adj, const float* __restrict__ Wh,
    const float* __restrict__ f1, const float* __restrict__ f2,
    float* __restrict__ out) {
  __shared__ float pL[8 * 2048];  // exactly 64 KB; reused as reduction buffer
  int t = threadIdx.x;
  int b = blockIdx.y;
  int i0 = blockIdx.x * 8;
  int w = t >> 6, lane = t & 63;
  int row = i0 + w;
  size_t gr = (size_t)b * NTOK + row;

  // ---- phase 1: scores for this wave's row (32 j per lane) ----
  float f1v = f1[gr];
  const int4* arow = (const int4*)(adj + ((size_t)b * NTOK + row) * NTOK);
  const float4* f2b = (const float4*)(f2 + (size_t)b * NTOK);
  float e[32];
  float mx = NEGV;
#pragma unroll
  for (int it = 0; it < 8; ++it) {
    int idx = it * 64 + lane;
    int4 av = arow[idx];
    float4 fv = f2b[idx];
    float s0 = f1v * fv.x, s1 = f1v * fv.y, s2 = f1v * fv.z, s3 = f1v * fv.w;
    float e0 = av.x > 0 ? (s0 > 0.f ? s0 : 0.01f * s0) : NEGV;
    float e1 = av.y > 0 ? (s1 > 0.f ? s1 : 0.01f * s1) : NEGV;
    float e2 = av.z > 0 ? (s2 > 0.f ? s2 : 0.01f * s2) : NEGV;
    float e3 = av.w > 0 ? (s3 > 0.f ? s3 : 0.01f * s3) : NEGV;
    e[it * 4 + 0] = e0; e[it * 4 + 1] = e1;
    e[it * 4 + 2] = e2; e[it * 4 + 3] = e3;
    mx = fmaxf(mx, fmaxf(fmaxf(e0, e1), fmaxf(e2, e3)));
  }
#pragma unroll
  for (int s = 32; s; s >>= 1) mx = fmaxf(mx, __shfl_xor(mx, s, 64));

  // ---- phase 2: exp + row sum; p kept unnormalized ----
  float sum = 0.f;
#pragma unroll
  for (int k = 0; k < 32; ++k) {
    float p = (e[k] > -4.0e15f) ? __expf(e[k] - mx) : 0.f;
    sum += p;
    e[k] = p;
  }
#pragma unroll
  for (int s = 32; s; s >>= 1) sum += __shfl_xor(sum, s, 64);
  float dn = sum;  // all lanes of wave w hold row w's denominator
#pragma unroll
  for (int it = 0; it < 8; ++it) {
    int idx = it * 64 + lane;
    float4 v = make_float4(e[it * 4 + 0], e[it * 4 + 1], e[it * 4 + 2], e[it * 4 + 3]);
    *(float4*)&pL[w * 2048 + idx * 4] = v;
  }
  __syncthreads();

  // ---- phase 3: acc[r][f0..f0+3] += p[r][j] * Wh[j][f0..f0+3] ----
  int l16 = t & 15;        // feature group: f0 = l16*4
  int sc = t >> 4;         // j-subchunk 0..31, 64 j each
  const float4* Wh4 = (const float4*)(Wh + (size_t)b * NTOK * 64);
  float4 acc[8];
#pragma unroll
  for (int r = 0; r < 8; ++r) acc[r] = make_float4(0.f, 0.f, 0.f, 0.f);
  for (int jj = 0; jj < 16; ++jj) {
    int j0 = sc * 64 + 4 * ((jj + sc) & 15);  // stagger: conflict-free p reads
    float4 wv0 = Wh4[(size_t)(j0 + 0) * 16 + l16];
    float4 wv1 = Wh4[(size_t)(j0 + 1) * 16 + l16];
    float4 wv2 = Wh4[(size_t)(j0 + 2) * 16 + l16];
    float4 wv3 = Wh4[(size_t)(j0 + 3) * 16 + l16];
#pragma unroll
    for (int r = 0; r < 8; ++r) {
      float4 pv = *(const float4*)&pL[r * 2048 + j0];
      acc[r].x += pv.x * wv0.x + pv.y * wv1.x + pv.z * wv2.x + pv.w * wv3.x;
      acc[r].y += pv.x * wv0.y + pv.y * wv1.y + pv.z * wv2.y + pv.w * wv3.y;
      acc[r].z += pv.x * wv0.z + pv.y * wv1.z + pv.z * wv2.z + pv.w * wv3.z;
      acc[r].w += pv.x * wv0.w + pv.y * wv1.w + pv.z * wv2.w + pv.w * wv3.w;
    }
  }
  // reduce the 4 sc-subgroups within each wave (lanes ^16, ^32)
#pragma unroll
  for (int r = 0; r < 8; ++r) {
    acc[r].x += __shfl_xor(acc[r].x, 16, 64);
    acc[r].y += __shfl_xor(acc[r].y, 16, 64);
    acc[r].z += __shfl_xor(acc[r].z, 16, 64);
    acc[r].w += __shfl_xor(acc[r].w, 16, 64);
    acc[r].x += __shfl_xor(acc[r].x, 32, 64);
    acc[r].y += __shfl_xor(acc[r].y, 32, 64);
    acc[r].z += __shfl_xor(acc[r].z, 32, 64);
    acc[r].w += __shfl_xor(acc[r].w, 32, 64);
  }
  __syncthreads();  // all p reads done; reuse pL as reduction buffer
  float* red = pL;
  if (lane < 16) {
#pragma unroll
    for (int r = 0; r < 8; ++r)
      *(float4*)&red[w * 512 + r * 64 + l16 * 4] = acc[r];
  }
  __syncthreads();
  // final: thread t -> row r == w, feature f == lane (so dn is wave-local)
  float s2 = 0.f;
#pragma unroll
  for (int wv = 0; wv < 8; ++wv) s2 += red[wv * 512 + w * 64 + lane];
  float rdn = dn > 0.f ? 1.0f / dn : 0.f;
  float hp = s2 * rdn;
  float o = hp > 0.f ? hp : expm1f(hp);
  out[gr * 64 + lane] = o;
}

extern "C" void kernel_launch(void* const* d_in, const int* in_sizes, int n_in,
                              void* d_out, int out_size, void* d_ws, size_t ws_size,
                              hipStream_t stream) {
  const float* h = (const float*)d_in[0];
  const int* adj = (const int*)d_in[1];
  const float* W = (const float*)d_in[2];
  const float* a = (const float*)d_in[3];
  float* out = (float*)d_out;

  float* Wh = (float*)d_ws;                  // 16384*64 floats = 4 MB
  float* f1 = Wh + (size_t)16384 * 64;       // 16384 floats
  float* f2 = f1 + 16384;                    // 16384 floats

  gat_pre<<<1024, 256, 0, stream>>>(h, W, a, Wh, f1, f2);
  gat_main<<<dim3(256, 8), 512, 0, stream>>>(adj, Wh, f1, f2, out);
}

// Round 2
// 91.545 us; speedup vs baseline: 1.4788x; 1.4788x over previous
//
#include <hip/hip_runtime.h>

#define NTOK 2048
#define NEGV -9.0e15f

typedef __attribute__((ext_vector_type(8))) short s8v;
typedef __attribute__((ext_vector_type(4))) float f32x4;

__device__ inline unsigned short f2bf(float f) {
  unsigned u = __builtin_bit_cast(unsigned, f);
  u += 0x7FFFu + ((u >> 16) & 1u);
  return (unsigned short)(u >> 16);
}

// ---- Kernel A: Wh = h@W (f32 regs), f1 = Wh@a1, f2 = Wh@a2, WhT = bf16(Wh)^T
__global__ __launch_bounds__(256) void gat_pre(
    const float* __restrict__ h, const float* __restrict__ W,
    const float* __restrict__ a, unsigned short* __restrict__ WhT,
    float* __restrict__ f1, float* __restrict__ f2) {
  __shared__ float wL[128 * 64];            // 32 KB
  __shared__ float hL[16 * 128];            // 8 KB
  __shared__ unsigned short tL[64 * 16];    // 2 KB transpose buffer
  int t = threadIdx.x;
  {
    const float4* W4 = (const float4*)W;
    float4* wL4 = (float4*)wL;
#pragma unroll
    for (int k = 0; k < 8; ++k) wL4[t + 256 * k] = W4[t + 256 * k];
    const float4* h4 = (const float4*)(h + (size_t)blockIdx.x * 16 * 128);
    float4* hL4 = (float4*)hL;
#pragma unroll
    for (int k = 0; k < 2; ++k) hL4[t + 256 * k] = h4[t + 256 * k];
  }
  __syncthreads();
  int w = t >> 6, lane = t & 63;
  float acc[4] = {0.f, 0.f, 0.f, 0.f};
  for (int kc = 0; kc < 128; kc += 32) {
    float wreg[32];
#pragma unroll
    for (int kk = 0; kk < 32; ++kk) wreg[kk] = wL[(kc + kk) * 64 + lane];
#pragma unroll
    for (int r = 0; r < 4; ++r) {
      const float* hrow = &hL[(w * 4 + r) * 128 + kc];
#pragma unroll
      for (int kk = 0; kk < 32; kk += 4) {
        float4 hv = *(const float4*)(hrow + kk);
        acc[r] += hv.x * wreg[kk] + hv.y * wreg[kk + 1] +
                  hv.z * wreg[kk + 2] + hv.w * wreg[kk + 3];
      }
    }
  }
  float a1 = a[lane], a2 = a[lane + 64];
  int row0 = blockIdx.x * 16 + w * 4;
#pragma unroll
  for (int r = 0; r < 4; ++r) {
    int row = row0 + r;
    float v1 = acc[r] * a1, v2 = acc[r] * a2;
#pragma unroll
    for (int s = 32; s; s >>= 1) {
      v1 += __shfl_xor(v1, s, 64);
      v2 += __shfl_xor(v2, s, 64);
    }
    if (lane == 0) { f1[row] = v1; f2[row] = v2; }
    tL[lane * 16 + w * 4 + r] = f2bf(acc[r]);
  }
  __syncthreads();
  // coalesced bf16 write of WhT[b][feat][tok]
  int b = (blockIdx.x * 16) / NTOK;
  int tok0 = (blockIdx.x * 16) % NTOK;
  int feat = t >> 2, rl = (t & 3) * 4;
  uint2 v = *(const uint2*)&tL[feat * 16 + rl];
  *(uint2*)(WhT + ((size_t)b * 64 + feat) * NTOK + tok0 + rl) = v;
}

// ---- Kernel B: masked softmax of rank-1 scores (VALU) + PV via bf16 MFMA ----
// grid (128, 8), 1024 threads = 16 waves. Wave w owns row i0+w for phase 1/2;
// in phase 3 wave w owns K-slice [w*128, w*128+128).
__global__ __launch_bounds__(1024, 4) void gat_main(
    const int* __restrict__ adj, const unsigned short* __restrict__ WhT,
    const float* __restrict__ f1, const float* __restrict__ f2,
    float* __restrict__ out) {
  __shared__ __align__(16) char pLb[65536];  // bf16 P[16][2048], XOR-swizzled
  __shared__ float dnL[16];
  int t = threadIdx.x;
  int b = blockIdx.y;
  int i0 = blockIdx.x * 16;
  int w = t >> 6, lane = t & 63;
  size_t gr = (size_t)b * NTOK + i0 + w;

  // ---- phase 1: scores for row (i0+w); lane covers j = (it*64+lane)*8+q ----
  float f1v = f1[gr];
  const int4* arow = (const int4*)(adj + gr * NTOK);
  const float4* f2b = (const float4*)(f2 + (size_t)b * NTOK);
  float e[32];
  float mx = NEGV;
#pragma unroll
  for (int it = 0; it < 4; ++it) {
    int q = it * 64 + lane;
    int4 a0 = arow[q * 2 + 0];
    int4 a1 = arow[q * 2 + 1];
    float4 v0 = f2b[q * 2 + 0];
    float4 v1 = f2b[q * 2 + 1];
    float sv[8] = {f1v * v0.x, f1v * v0.y, f1v * v0.z, f1v * v0.w,
                   f1v * v1.x, f1v * v1.y, f1v * v1.z, f1v * v1.w};
    int am[8] = {a0.x, a0.y, a0.z, a0.w, a1.x, a1.y, a1.z, a1.w};
#pragma unroll
    for (int qq = 0; qq < 8; ++qq) {
      float s = sv[qq];
      float lk = s > 0.f ? s : 0.01f * s;
      float ev = am[qq] > 0 ? lk : NEGV;
      e[it * 8 + qq] = ev;
      mx = fmaxf(mx, ev);
    }
  }
#pragma unroll
  for (int s = 32; s; s >>= 1) mx = fmaxf(mx, __shfl_xor(mx, s, 64));

  // ---- phase 2: exp + row sum; store unnormalized bf16 P into LDS ----
  float sum = 0.f;
#pragma unroll
  for (int k = 0; k < 32; ++k) {
    float p = (e[k] > -4.0e15f) ? __expf(e[k] - mx) : 0.f;
    sum += p;
    e[k] = p;
  }
#pragma unroll
  for (int s = 32; s; s >>= 1) sum += __shfl_xor(sum, s, 64);
  if (lane == 0) dnL[w] = sum;
#pragma unroll
  for (int it = 0; it < 4; ++it) {
    int q = it * 64 + lane;
    s8v sv;
#pragma unroll
    for (int qq = 0; qq < 8; ++qq) sv[qq] = (short)f2bf(e[it * 8 + qq]);
    int off = (w * 4096 + q * 16) ^ ((w & 7) << 4);
    *(s8v*)(pLb + off) = sv;
  }
  __syncthreads();

  // ---- phase 3: C[16,64] += P[16, k-slice] @ Wh[k-slice, 64] via MFMA ----
  int l15 = lane & 15, lhi = lane >> 4;
  f32x4 ac0 = {0.f, 0.f, 0.f, 0.f}, ac1 = ac0, ac2 = ac0, ac3 = ac0;
  const unsigned short* WhB = WhT + (size_t)b * 64 * NTOK;
#pragma unroll
  for (int ks = 0; ks < 4; ++ks) {
    int k0 = w * 128 + ks * 32;
    int abyte = (l15 * 4096 + (k0 + lhi * 8) * 2) ^ ((l15 & 7) << 4);
    s8v af = *(const s8v*)(pLb + abyte);
    const unsigned short* bp = WhB + (size_t)l15 * NTOK + k0 + lhi * 8;
    s8v bf0 = *(const s8v*)(bp);
    s8v bf1 = *(const s8v*)(bp + 16 * NTOK);
    s8v bf2 = *(const s8v*)(bp + 32 * NTOK);
    s8v bf3 = *(const s8v*)(bp + 48 * NTOK);
    ac0 = __builtin_amdgcn_mfma_f32_16x16x32_bf16(af, bf0, ac0, 0, 0, 0);
    ac1 = __builtin_amdgcn_mfma_f32_16x16x32_bf16(af, bf1, ac1, 0, 0, 0);
    ac2 = __builtin_amdgcn_mfma_f32_16x16x32_bf16(af, bf2, ac2, 0, 0, 0);
    ac3 = __builtin_amdgcn_mfma_f32_16x16x32_bf16(af, bf3, ac3, 0, 0, 0);
  }
  __syncthreads();  // all P reads done; reuse pLb as f32 partial buffer
  float* pLf = (float*)pLb;
  {
    f32x4* dst = (f32x4*)pLb;
    dst[w * 256 + 0 * 64 + lane] = ac0;
    dst[w * 256 + 1 * 64 + lane] = ac1;
    dst[w * 256 + 2 * 64 + lane] = ac2;
    dst[w * 256 + 3 * 64 + lane] = ac3;
  }
  __syncthreads();

  // ---- epilogue: reduce 16 wave-partials, normalize, ELU, store ----
  int m = t >> 6, f = t & 63;  // output element (row m, feat f)
  int base = (f >> 4) * 256 + ((m >> 2) * 16 + (f & 15)) * 4 + (m & 3);
  float s2 = 0.f;
#pragma unroll
  for (int w2 = 0; w2 < 16; ++w2) s2 += pLf[w2 * 1024 + base];
  float dn = dnL[m];
  float rdn = dn > 0.f ? 1.0f / dn : 0.f;
  float hp = s2 * rdn;
  float o = hp > 0.f ? hp : expm1f(hp);
  out[((size_t)b * NTOK + i0 + m) * 64 + f] = o;
}

extern "C" void kernel_launch(void* const* d_in, const int* in_sizes, int n_in,
                              void* d_out, int out_size, void* d_ws, size_t ws_size,
                              hipStream_t stream) {
  const float* h = (const float*)d_in[0];
  const int* adj = (const int*)d_in[1];
  const float* W = (const float*)d_in[2];
  const float* a = (const float*)d_in[3];
  float* out = (float*)d_out;

  unsigned short* WhT = (unsigned short*)d_ws;            // 8*64*2048 bf16 = 2 MB
  float* f1 = (float*)((char*)d_ws + 2 * 1024 * 1024);    // 16384 f32
  float* f2 = f1 + 16384;                                 // 16384 f32

  gat_pre<<<1024, 256, 0, stream>>>(h, W, a, WhT, f1, f2);
  gat_main<<<dim3(128, 8), 1024, 0, stream>>>(adj, WhT, f1, f2, out);
}